// Round 2
// 208.517 us; speedup vs baseline: 1.6103x; 1.6103x over previous
//
#include <hip/hip_runtime.h>

#define B_    32
#define C_    512
#define HW2_  1024
#define NW    77
#define NP    80     // n padded to 80 (5 x 16 MFMA rows)
#define NPT   96     // n pitch for weT / P (3 K-steps of 32), cols >=77 zeroed
#define WD    256

typedef unsigned int   uint32;
typedef unsigned short u16;
typedef __attribute__((ext_vector_type(8))) short bf16x8;  // MFMA A/B frag (4 VGPR)
typedef __attribute__((ext_vector_type(4))) float f32x4;   // MFMA C/D frag

#define MFMA(a, b, c) __builtin_amdgcn_mfma_f32_16x16x32_bf16(a, b, c, 0, 0, 0)

// fp32 -> (hi, lo) bf16 split. hi = truncation (1 op), residual is exact,
// lo = RNE(residual). Pair represents x to ~2^-17 relative.
__device__ __forceinline__ void split1(float x, u16 &h, u16 &l) {
    uint32 u = __float_as_uint(x);
    h = (u16)(u >> 16);
    float r = x - __uint_as_float(u & 0xffff0000u);   // exact
    uint32 v = __float_as_uint(r);
    l = (u16)((v + 0x7fffu + ((v >> 16) & 1u)) >> 16);
}

__device__ __forceinline__ void split8(float4 a, float4 b, bf16x8 &h, bf16x8 &l) {
    float v[8] = {a.x, a.y, a.z, a.w, b.x, b.y, b.z, b.w};
    #pragma unroll
    for (int i = 0; i < 8; ++i) {
        u16 hh, ll; split1(v[i], hh, ll);
        h[i] = (short)hh; l[i] = (short)ll;
    }
}

// ---------------------------------------------------------------------------
// Kernel 1: we = word_emb @ W_fc^T + b_fc via MFMA (4-term split: full acc).
// Writes we_hi/lo [b][n][k] (phase-1 A) and weT_hi/lo [b][k][n] (phase-3 A).
// grid 512 = 32 b x 16 kout-chunks of 64, 256 thr = 4 waves.
// Wave w owns kout tile 16w of the 64-chunk, all 5 n-tiles, K=256.
// ---------------------------------------------------------------------------
__global__ __launch_bounds__(256) void we_gemm(
    const float* __restrict__ word_emb, const float* __restrict__ W_fc,
    const float* __restrict__ b_fc,
    bf16x8* __restrict__ we_hi, bf16x8* __restrict__ we_lo,
    bf16x8* __restrict__ weT_hi, bf16x8* __restrict__ weT_lo)
{
    __shared__ __align__(16) float D[NP][68];   // 21.75 KB, fp32 result tile

    const int id   = blockIdx.x;
    const int b    = id >> 4;
    const int kb   = (id & 15) * 64;
    const int t    = threadIdx.x;
    const int w    = t >> 6, lane = t & 63;
    const int lr   = lane & 15, lg = lane >> 4;
    const int kout = kb + 16 * w + lr;          // lane's D column

    f32x4 acc[5];
    #pragma unroll
    for (int m = 0; m < 5; ++m) acc[m] = (f32x4)0.0f;

    const float* wrow = W_fc + kout * WD;
    const float* emb  = word_emb + b * NW * WD;

    for (int ks = 0; ks < 8; ++ks) {
        const int dk = ks * 32 + 8 * lg;
        bf16x8 bh, bl;
        {   float4 x = *(const float4*)(wrow + dk);
            float4 y = *(const float4*)(wrow + dk + 4);
            split8(x, y, bh, bl); }
        bf16x8 ah[5], al[5];
        #pragma unroll
        for (int m = 0; m < 5; ++m) {
            const int n = 16 * m + lr;
            float4 x = make_float4(0.f, 0.f, 0.f, 0.f), y = x;
            if (n < NW) {
                const float* ap = emb + n * WD + dk;
                x = *(const float4*)ap; y = *(const float4*)(ap + 4);
            }
            split8(x, y, ah[m], al[m]);
        }
        #pragma unroll
        for (int m = 0; m < 5; ++m) {
            acc[m] = MFMA(ah[m], bh, acc[m]);
            acc[m] = MFMA(ah[m], bl, acc[m]);
            acc[m] = MFMA(al[m], bh, acc[m]);
            acc[m] = MFMA(al[m], bl, acc[m]);   // 4th term: we must be accurate
        }
    }

    const float bias = b_fc[kout];
    #pragma unroll
    for (int m = 0; m < 5; ++m)
        #pragma unroll
        for (int r = 0; r < 4; ++r)
            D[16 * m + 4 * lg + r][16 * w + lr] = acc[m][r] + bias;
    __syncthreads();

    // we_hi/lo [b][n][kb..kb+64], rows n>=77 zeroed
    for (int u = t; u < NP * 8; u += 256) {
        const int n = u >> 3, c8 = (u & 7) * 8;
        bf16x8 h, l;
        if (n < NW) {
            float4 x = *(const float4*)&D[n][c8];
            float4 y = *(const float4*)&D[n][c8 + 4];
            split8(x, y, h, l);
        } else { h = (bf16x8)(short)0; l = (bf16x8)(short)0; }
        const int o = ((b * NP + n) * HW2_ + kb + c8) >> 3;
        we_hi[o] = h; we_lo[o] = l;
    }
    // weT_hi/lo [b][kout][n] pitch 96, cols n>=77 zeroed. threads 0..63 -> hi,
    // 64..127 -> lo; column reads of D are lane-consecutive (conflict-free).
    if (t < 128) {
        const int kr  = t & 63;
        const int sel = t >> 6;
        bf16x8* dst = (sel ? weT_lo : weT_hi) + (((b * HW2_ + kb + kr) * NPT) >> 3);
        #pragma unroll
        for (int g = 0; g < 12; ++g) {
            bf16x8 v;
            #pragma unroll
            for (int i = 0; i < 8; ++i) {
                const int n = g * 8 + i;
                float x = (n < NW) ? D[n][kr] : 0.f;
                u16 h, l; split1(x, h, l);
                v[i] = (short)(sel ? l : h);
            }
            dst[g] = v;
        }
    }
}

// ---------------------------------------------------------------------------
// Kernel 2: fused scores^T -> softmax -> out via MFMA (3-term split).
// Block = 256 thr = 4 waves = ONE 16-row c-strip, 4-way K-split in phase 1.
// grid 1024 = 32 b x 32 strips, XCD-swizzled so each batch stays on one XCD.
// No LDS tile staging: fragments come straight from L2-resident we/weT.
// ---------------------------------------------------------------------------
__global__ __launch_bounds__(256, 2) void attn_mfma(
    const float* __restrict__ feat,
    const bf16x8* __restrict__ we_hi, const bf16x8* __restrict__ we_lo,
    const bf16x8* __restrict__ weT_hi, const bf16x8* __restrict__ weT_lo,
    float* __restrict__ out)
{
    __shared__ __align__(16) float S[3][16][84];   // partial scores (16.1 KB)
    __shared__ __align__(16) u16   Ph[16][NPT];    // P hi (3 KB)
    __shared__ __align__(16) u16   Pl[16][NPT];    // P lo (3 KB)

    const int id  = blockIdx.x;
    const int q   = id >> 3;
    const int b   = (id & 7) + 8 * (q >> 5);          // batch -> XCD id&7
    const int c0  = (q & 31) * 16;                    // strip's 16 c rows

    const int t    = threadIdx.x;
    const int h    = t >> 6;                          // wave = K-quarter
    const int lane = t & 63, lr = lane & 15, lg = lane >> 4;

    // ---- Phase 1: scores^T[n][c] = we . f^T, K quarter per wave -----------
    f32x4 acc[5];
    #pragma unroll
    for (int m = 0; m < 5; ++m) acc[m] = (f32x4)0.0f;

    const float*  frow = feat + (size_t)(b * C_ + c0 + lr) * HW2_;
    const bf16x8* wh   = we_hi + ((size_t)b * NP * HW2_ >> 3);
    const bf16x8* wl   = we_lo + ((size_t)b * NP * HW2_ >> 3);

    for (int ks = 0; ks < 8; ++ks) {
        const int kk = h * 256 + ks * 32 + 8 * lg;
        bf16x8 fh, fl;
        {   float4 x = *(const float4*)(frow + kk);
            float4 y = *(const float4*)(frow + kk + 4);
            split8(x, y, fh, fl); }
        bf16x8 ah[5], al[5];
        #pragma unroll
        for (int m = 0; m < 5; ++m) {
            const int o = ((16 * m + lr) * HW2_ + kk) >> 3;
            ah[m] = wh[o];
            al[m] = wl[o];
        }
        #pragma unroll
        for (int m = 0; m < 5; ++m) {
            acc[m] = MFMA(ah[m], fh, acc[m]);
            acc[m] = MFMA(ah[m], fl, acc[m]);
            acc[m] = MFMA(al[m], fh, acc[m]);
        }
    }

    if (h < 3) {
        #pragma unroll
        for (int m = 0; m < 5; ++m)
            #pragma unroll
            for (int r = 0; r < 4; ++r)
                S[h][lr][16 * m + 4 * lg + r] = acc[m][r];
    }
    __syncthreads();

    // ---- merge + softmax over n (wave 3), in-lane 20 + shfl_xor(16,32) ----
    if (h == 3) {
        float sc[5][4], mx = -3.0e38f;
        #pragma unroll
        for (int m = 0; m < 5; ++m)
            #pragma unroll
            for (int r = 0; r < 4; ++r) {
                const int n = 16 * m + 4 * lg + r;
                float v = acc[m][r] + S[0][lr][n] + S[1][lr][n] + S[2][lr][n];
                sc[m][r] = v;
                if (n < NW) mx = fmaxf(mx, v);
            }
        mx = fmaxf(mx, __shfl_xor(mx, 16));
        mx = fmaxf(mx, __shfl_xor(mx, 32));
        float sum = 0.f, e[5][4];
        #pragma unroll
        for (int m = 0; m < 5; ++m)
            #pragma unroll
            for (int r = 0; r < 4; ++r) {
                const int n = 16 * m + 4 * lg + r;
                float v = (n < NW) ? __expf(sc[m][r] - mx) : 0.f;
                e[m][r] = v; sum += v;
            }
        sum += __shfl_xor(sum, 16);
        sum += __shfl_xor(sum, 32);
        const float inv = 1.0f / sum;
        #pragma unroll
        for (int m = 0; m < 5; ++m)
            #pragma unroll
            for (int r = 0; r < 4; ++r) {
                const int n = 16 * m + 4 * lg + r;
                u16 ph, pl; split1(e[m][r] * inv, ph, pl);
                Ph[lr][n] = ph; Pl[lr][n] = pl;
            }
    } else if (h == 0) {                    // zero the n = 80..95 pad
        #pragma unroll
        for (int r = 0; r < 4; ++r) { Ph[lr][80 + 4 * lg + r] = 0; Pl[lr][80 + 4 * lg + r] = 0; }
    }
    __syncthreads();

    // ---- Phase 3: out^T[kout][c] = weT . P^T; wave h takes 4 kout-chunks --
    bf16x8 pbh[3], pbl[3];
    #pragma unroll
    for (int ksn = 0; ksn < 3; ++ksn) {     // hoisted B-frags (P), reused 16x
        pbh[ksn] = *(const bf16x8*)&Ph[lr][32 * ksn + 8 * lg];
        pbl[ksn] = *(const bf16x8*)&Pl[lr][32 * ksn + 8 * lg];
    }
    const bf16x8* th = weT_hi + ((size_t)b * HW2_ * NPT >> 3);
    const bf16x8* tl = weT_lo + ((size_t)b * HW2_ * NPT >> 3);
    float* orow = out + (size_t)(b * C_ + c0 + lr) * HW2_;

    for (int ci = 0; ci < 4; ++ci) {
        const int kb = (ci * 4 + h) * 64;
        f32x4 o[4];
        #pragma unroll
        for (int kt = 0; kt < 4; ++kt) o[kt] = (f32x4)0.0f;
        #pragma unroll
        for (int kt = 0; kt < 4; ++kt) {
            const int rbase = ((kb + 16 * kt + lr) * NPT) >> 3;
            #pragma unroll
            for (int ksn = 0; ksn < 3; ++ksn) {
                bf16x8 wa = th[rbase + (32 * ksn + 8 * lg) / 8];
                bf16x8 wb = tl[rbase + (32 * ksn + 8 * lg) / 8];
                o[kt] = MFMA(wa, pbh[ksn], o[kt]);
                o[kt] = MFMA(wa, pbl[ksn], o[kt]);
                o[kt] = MFMA(wb, pbh[ksn], o[kt]);
            }
        }
        #pragma unroll
        for (int kt = 0; kt < 4; ++kt) {    // D regs = 4 consecutive kout -> float4
            float4 v = make_float4(o[kt][0], o[kt][1], o[kt][2], o[kt][3]);
            *(float4*)(orow + kb + 16 * kt + 4 * lg) = v;
        }
    }
}

// ---------------------------------------------------------------------------
extern "C" void kernel_launch(void* const* d_in, const int* in_sizes, int n_in,
                              void* d_out, int out_size, void* d_ws, size_t ws_size,
                              hipStream_t stream) {
    (void)in_sizes; (void)n_in; (void)out_size; (void)ws_size;
    const float* feat     = (const float*)d_in[0];
    const float* word_emb = (const float*)d_in[1];
    const float* W_fc     = (const float*)d_in[2];
    const float* b_fc     = (const float*)d_in[3];

    // workspace: ~23 MB of bf16 hi/lo planes (element = bf16x8 = 16 B)
    bf16x8* we_hi  = (bf16x8*)d_ws;
    bf16x8* we_lo  = we_hi  + ((size_t)B_ * NP * HW2_ >> 3);
    bf16x8* weT_hi = we_lo  + ((size_t)B_ * NP * HW2_ >> 3);
    bf16x8* weT_lo = weT_hi + ((size_t)B_ * HW2_ * NPT >> 3);

    we_gemm<<<512, 256, 0, stream>>>(word_emb, W_fc, b_fc, we_hi, we_lo, weT_hi, weT_lo);
    attn_mfma<<<1024, 256, 0, stream>>>(feat, we_hi, we_lo, weT_hi, weT_lo, (float*)d_out);
}